// Round 5
// baseline (203.240 us; speedup 1.0000x reference)
//
#include <hip/hip_runtime.h>
#include <hip/hip_bf16.h>
#include <math.h>

#define N_NODES 50000
#define N_EDGES 600000
#define D_IN 256
#define D_GNN 128
#define CAP 32        // padded adjacency slots per node (ushort); 1 cache line
#define MAX_OVER 8192
#define NBLK 512      // persistent blocks: 2/CU resident
#define NTILES 3125   // 50000 / 16
#define EB_STRIDE 264 // epilogue LDS bf16 row stride: 528 B = 16B-aligned rows,
                      // measured 0 bank conflicts in R3. (R4's 76 -> 152B rows
                      // broke b128 alignment -> reverted.)

typedef short s16x8 __attribute__((ext_vector_type(8)));
typedef float f32x4 __attribute__((ext_vector_type(4)));

__device__ __forceinline__ unsigned short f2bf(float f) {
  unsigned int u = __float_as_uint(f);
  u += 0x7FFFu + ((u >> 16) & 1u);  // RNE
  return (unsigned short)(u >> 16);
}

// ---------------------------------------------------------------------------
// Prologue: zero cursor[] + overflow count + pack Wc=[W_l|W_r] to B-fragment
// order (bf16): Wcp[((ks*256+col)*4+q)*8+j] = [Wl|Wr][ks*32+q*8+j][col]
// ---------------------------------------------------------------------------
__global__ __launch_bounds__(256) void pack0(
    const float* __restrict__ Wl, const float* __restrict__ Wr,
    ushort* __restrict__ Wcp, int* __restrict__ cursor,
    int* __restrict__ ovcnt) {
  int i = blockIdx.x * 256 + threadIdx.x;
  if (i < N_NODES) cursor[i] = 0;
  if (i == 0) ovcnt[0] = 0;
  if (i < 8192) {  // one 16B B-fragment per thread
    int q = i & 3, col = (i >> 2) & 255, ks = i >> 10;
    const float* W = (col < 128) ? Wl : Wr;
    int c = col & 127;
    int k0 = ks * 32 + q * 8;
    s16x8 v;
#pragma unroll
    for (int j = 0; j < 8; j++) v[j] = (short)f2bf(W[(k0 + j) * D_GNN + c]);
    *((s16x8*)(Wcp + (size_t)i * 8)) = v;
  }
}

// ---------------------------------------------------------------------------
// FUSED kernel (R5 = R4 theory + alignment fix): PERSISTENT-WAVE MFMA GEMM +
// edge scatter.
//   Evidence: R1 (async-LDS, 2 blk/CU) and R3 (direct loads, 69% occupancy,
//   VGPR=32) both pinned at ~1.2 TB/s; fillBuffer hits 6.5 TB/s at 8%
//   occupancy -> limiter is per-wave bytes-in-flight x block lifetime.
//   Fix: 512 persistent blocks (2/CU, 256-VGPR budget); wave owns a 64-col
//   B-slice in 128 VGPRs (loaded once, L2-resident); grid-stride over ~6
//   row-tiles; per tile ALL 16 independent float4 x-loads issued as one
//   batch (64 VGPRs live) -> deep steady-state MLP. Epilogue: R3-proven
//   block-level eb[16][264] transpose (16B-aligned rows, 0 conflicts) with
//   two __syncthreads per tile (tile loop is block-uniform). Edge scatter
//   fused at kernel start (R2: overlap ~free).
// ---------------------------------------------------------------------------
__global__ __launch_bounds__(256, 2) void fused_gemm_fill(
    const float* __restrict__ x, const ushort* __restrict__ Wcp,
    const float* __restrict__ b_l, const int* __restrict__ ei,
    int* __restrict__ cursor, ushort* __restrict__ colp,
    int* __restrict__ ovcnt, int2* __restrict__ over,
    ushort* __restrict__ yb, ushort* __restrict__ yrb) {
  __shared__ ushort eb[16 * EB_STRIDE];  // 8448 B block-level transpose buffer
  const int t = threadIdx.x;
  const int l = t & 63;
  const int w = t >> 6;              // wave = 64-col slice
  const int lq = l >> 4, l16 = l & 15;

  // --- edge phase: <=5 edges/thread; atomic+scatter drains in background ---
  for (int e = blockIdx.x * 256 + t; e < N_EDGES; e += NBLK * 256) {
    int esrc = ei[e];
    int edst = ei[N_EDGES + e];
    int pos = atomicAdd(&cursor[edst], 1);
    if (pos < CAP) {
      colp[edst * CAP + pos] = (ushort)esrc;
    } else {
      int o = atomicAdd(ovcnt, 1);
      if (o < MAX_OVER) over[o] = make_int2(edst, esrc);
    }
  }

  // --- B-slice -> 128 VGPRs (once; L2-resident Wcp) ---
  const int c0 = w * 64;
  s16x8 Breg[4][8];
  float bias[4];
#pragma unroll
  for (int ct = 0; ct < 4; ct++) {
    int col = c0 + ct * 16 + l16;
    const ushort* bp = Wcp + ((size_t)col * 4 + lq) * 8;
#pragma unroll
    for (int ks = 0; ks < 8; ks++)
      Breg[ct][ks] = *((const s16x8*)(bp + (size_t)ks * 8192));
    bias[ct] = (col >= 128) ? b_l[col - 128] : 0.f;
  }

  // --- persistent tile loop: tile = 16 rows x 256 k; 4 waves split cols.
  //     Tile count is block-uniform -> __syncthreads inside is safe. ---
  for (int tt = blockIdx.x; tt < NTILES; tt += NBLK) {
    const int n0 = tt * 16;  // 3125*16 = 50000 exactly; no row clamp needed
    const float* ap = x + (size_t)(n0 + l16) * D_IN + lq * 8;

    // batched independent loads: the MLP driver
    float4 av[16];
#pragma unroll
    for (int k2 = 0; k2 < 16; k2++)
      av[k2] = *((const float4*)(ap + (k2 >> 1) * 32 + (k2 & 1) * 4));

    f32x4 acc[4];
#pragma unroll
    for (int ct = 0; ct < 4; ct++) acc[ct] = (f32x4){0.f, 0.f, 0.f, 0.f};

#pragma unroll
    for (int ks = 0; ks < 8; ks++) {
      float4 a0 = av[2 * ks], a1 = av[2 * ks + 1];
      union { s16x8 v; ushort4 u[2]; } ua;
      __hip_bfloat162 h0 = __float22bfloat162_rn(make_float2(a0.x, a0.y));
      __hip_bfloat162 h1 = __float22bfloat162_rn(make_float2(a0.z, a0.w));
      __hip_bfloat162 h2 = __float22bfloat162_rn(make_float2(a1.x, a1.y));
      __hip_bfloat162 h3 = __float22bfloat162_rn(make_float2(a1.z, a1.w));
      ua.u[0].x = ((ushort2*)&h0)->x; ua.u[0].y = ((ushort2*)&h0)->y;
      ua.u[0].z = ((ushort2*)&h1)->x; ua.u[0].w = ((ushort2*)&h1)->y;
      ua.u[1].x = ((ushort2*)&h2)->x; ua.u[1].y = ((ushort2*)&h2)->y;
      ua.u[1].z = ((ushort2*)&h3)->x; ua.u[1].w = ((ushort2*)&h3)->y;
      s16x8 A = ua.v;
#pragma unroll
      for (int ct = 0; ct < 4; ct++)
        acc[ct] = __builtin_amdgcn_mfma_f32_16x16x32_bf16(
            A, Breg[ct][ks], acc[ct], 0, 0, 0);
    }

    // --- epilogue: acc -> LDS bf16 -> b128 stores (block-level, R3 layout) ---
    // C/D layout: col = lane&15, row = lq*4 + reg  [m89/m91-verified]
#pragma unroll
    for (int ct = 0; ct < 4; ct++) {
      int col = c0 + ct * 16 + l16;  // 0..255
#pragma unroll
      for (int r = 0; r < 4; r++)
        eb[(lq * 4 + r) * EB_STRIDE + col] = f2bf(acc[ct][r] + bias[ct]);
    }
    __syncthreads();
#pragma unroll
    for (int p = 0; p < 2; p++) {
      int id = p * 256 + t;       // 0..511
      int rl = id >> 5;           // 0..15
      int c8 = (id & 31) * 8;     // 0..248
      s16x8 v = *((const s16x8*)(eb + rl * EB_STRIDE + c8));
      int gn = n0 + rl;
      if (c8 < 128)
        *((s16x8*)(yb + (size_t)gn * D_GNN + c8)) = v;
      else
        *((s16x8*)(yrb + (size_t)gn * D_GNN + (c8 - 128))) = v;
    }
    __syncthreads();  // all reads of eb done before next tile's writes
  }
}

// ---------------------------------------------------------------------------
// Gather (padded adjacency, ushort cols) + epilogue + pred head. One wave per
// node; lane owns dims {2*lane, 2*lane+1}. True degree = cursor[node]; first
// min(deg,CAP) neighbors in colp[node*CAP..] (one 64B line), rest in the
// exact overflow list (wave-uniform scan, expected ~0 entries).
// ---------------------------------------------------------------------------
__global__ __launch_bounds__(256) void gather_pred(
    const int* __restrict__ cursor, const ushort* __restrict__ colp,
    const int* __restrict__ ovcnt, const int2* __restrict__ over,
    const ushort* __restrict__ yb, const ushort* __restrict__ yrb,
    const float* __restrict__ Wfc, const float* __restrict__ bfc,
    float* __restrict__ h, float* __restrict__ pred) {
  const int node = (blockIdx.x * 256 + threadIdx.x) >> 6;
  const int lane = threadIdx.x & 63;
  if (node >= N_NODES) return;
  const int degt = cursor[node];
  const int m = min(degt, CAP);
  float ax = 0.f, ay = 0.f;
  const unsigned int* y32 = (const unsigned int*)yb;

  int c = (lane < m) ? (int)colp[node * CAP + lane] : 0;
  int j = 0;
  for (; j + 4 <= m; j += 4) {
    int s0 = __shfl(c, j), s1 = __shfl(c, j + 1);
    int s2 = __shfl(c, j + 2), s3 = __shfl(c, j + 3);
    unsigned int v0 = y32[(size_t)s0 * 64 + lane];
    unsigned int v1 = y32[(size_t)s1 * 64 + lane];
    unsigned int v2 = y32[(size_t)s2 * 64 + lane];
    unsigned int v3 = y32[(size_t)s3 * 64 + lane];
    ax += __uint_as_float(v0 << 16) + __uint_as_float(v1 << 16) +
          __uint_as_float(v2 << 16) + __uint_as_float(v3 << 16);
    ay += __uint_as_float(v0 & 0xFFFF0000u) + __uint_as_float(v1 & 0xFFFF0000u) +
          __uint_as_float(v2 & 0xFFFF0000u) + __uint_as_float(v3 & 0xFFFF0000u);
  }
  for (; j < m; j++) {
    int s0 = __shfl(c, j);
    unsigned int v0 = y32[(size_t)s0 * 64 + lane];
    ax += __uint_as_float(v0 << 16);
    ay += __uint_as_float(v0 & 0xFFFF0000u);
  }
  if (degt > CAP) {  // exact overflow handling (rare; wave-uniform)
    int nov = min(ovcnt[0], MAX_OVER);
    for (int k = 0; k < nov; k++) {
      int2 ov = over[k];
      if (ov.x == node) {
        unsigned int v0 = y32[(size_t)ov.y * 64 + lane];
        ax += __uint_as_float(v0 << 16);
        ay += __uint_as_float(v0 & 0xFFFF0000u);
      }
    }
  }

  const float ic = degt > 0 ? 1.f / (float)degt : 0.f;
  unsigned int yrv = ((const unsigned int*)yrb)[(size_t)node * 64 + lane];
  float h0 = ax * ic + __uint_as_float(yrv << 16);
  float h1 = ay * ic + __uint_as_float(yrv & 0xFFFF0000u);
  float2 hv; hv.x = h0; hv.y = h1;
  ((float2*)h)[(size_t)node * 64 + lane] = hv;
  float s = h0 * Wfc[2 * lane] + h1 * Wfc[2 * lane + 1];
#pragma unroll
  for (int off = 32; off > 0; off >>= 1) s += __shfl_down(s, off);
  if (lane == 0) pred[node] = 1.f / (1.f + expf(-(s + bfc[0])));
}

extern "C" void kernel_launch(void* const* d_in, const int* in_sizes, int n_in,
                              void* d_out, int out_size, void* d_ws,
                              size_t ws_size, hipStream_t stream) {
  const float* x   = (const float*)d_in[0];
  const int*   ei  = (const int*)d_in[1];
  const float* Wl  = (const float*)d_in[2];
  const float* bl  = (const float*)d_in[3];
  const float* Wr  = (const float*)d_in[4];
  const float* Wfc = (const float*)d_in[5];
  const float* bfc = (const float*)d_in[6];

  float* out  = (float*)d_out;
  float* h    = out;                        // [N,128] final h (f32)
  float* pred = out + (size_t)N_NODES * D_GNN;

  ushort* Wcp   = (ushort*)d_ws;                              // 128 KB
  ushort* yb    = Wcp + 8192 * 8;                             // [N,128] bf16
  ushort* yrb   = yb + (size_t)N_NODES * D_GNN;               // [N,128] bf16
  int*   cursor = (int*)(yrb + (size_t)N_NODES * D_GNN);      // [N]
  int*   ovcnt  = cursor + N_NODES;                           // [1]
  int2*  over   = (int2*)(ovcnt + 1);                         // [MAX_OVER]
  ushort* colp  = (ushort*)(over + MAX_OVER);                 // [N*CAP] ushort

  // --- prologue: zero cursor/ovcnt + pack W ---
  pack0<<<(N_NODES + 255) / 256, 256, 0, stream>>>(Wl, Wr, Wcp, cursor, ovcnt);

  // --- fused: persistent-wave GEMM + adjacency scatter ---
  fused_gemm_fill<<<NBLK, 256, 0, stream>>>(
      x, Wcp, bl, ei, cursor, colp, ovcnt, over, yb, yrb);

  // --- mean gather + h epilogue + pred head ---
  gather_pred<<<(N_NODES * 64 + 255) / 256, 256, 0, stream>>>(
      cursor, colp, ovcnt, over, yb, yrb, Wfc, bfc, h, pred);
}

// Round 6
// 170.836 us; speedup vs baseline: 1.1897x; 1.1897x over previous
//
#include <hip/hip_runtime.h>
#include <hip/hip_bf16.h>
#include <math.h>

#define N_NODES 50000
#define N_EDGES 600000
#define D_IN 256
#define D_GNN 128
#define CAP 32        // padded adjacency slots per node (ushort); 1 cache line
#define MAX_OVER 8192
#define CSTRIDE 16    // cursor padded to 1 int per 64B line: 12 atomics/line
                      // instead of 192 -> cross-XCD serialization tail /16

typedef short s16x8 __attribute__((ext_vector_type(8)));
typedef float f32x4 __attribute__((ext_vector_type(4)));

__device__ __forceinline__ unsigned short f2bf(float f) {
  unsigned int u = __float_as_uint(f);
  u += 0x7FFFu + ((u >> 16) & 1u);  // RNE
  return (unsigned short)(u >> 16);
}

// ---------------------------------------------------------------------------
// Prologue: zero padded cursor[] + overflow count + pack Wc=[W_l|W_r] to
// B-fragment order (bf16): Wcp[((ks*256+col)*4+q)*8+j] = [Wl|Wr][ks*32+q*8+j][col]
// ---------------------------------------------------------------------------
__global__ __launch_bounds__(256) void pack0(
    const float* __restrict__ Wl, const float* __restrict__ Wr,
    ushort* __restrict__ Wcp, int* __restrict__ cursor,
    int* __restrict__ ovcnt) {
  int i = blockIdx.x * 256 + threadIdx.x;
  if (i < N_NODES * CSTRIDE) cursor[i] = 0;
  if (i == 0) ovcnt[0] = 0;
  if (i < 8192) {  // one 16B B-fragment per thread
    int q = i & 3, col = (i >> 2) & 255, ks = i >> 10;
    const float* W = (col < 128) ? Wl : Wr;
    int c = col & 127;
    int k0 = ks * 32 + q * 8;
    s16x8 v;
#pragma unroll
    for (int j = 0; j < 8; j++) v[j] = (short)f2bf(W[(k0 + j) * D_GNN + c]);
    *((s16x8*)(Wcp + (size_t)i * 8)) = v;
  }
}

// ---------------------------------------------------------------------------
// FUSED kernel (R6 = R2 structure + contention fixes): MFMA GEMM + edge
// adjacency build.
//   R2 (this exact GEMM) measured 56us fused / 44us pure-GEMM; R3/R5
//   restructures both regressed -> structure reverted to R2. New deltas:
//   cursor line-padded (CSTRIDE) and colp ushort, attacking the 600K-atomic
//   cross-XCD serialization tail (fill_pad standalone was 42us; cursor was
//   192 atomics/line).
//   GEMM: [y_l|y_r] = x @ [W_l|W_r]; block = 64 rows x 256 cols, 8 waves;
//   x staged f32->LDS via async global_load_lds w=16 (source-chunk swizzle,
//   read-side same involution); bf16 cvt at A-read; B prefetch 1 K-step.
//   Epilogue: acc -> LDS bf16 (padded stride) -> b128 stores.
// ---------------------------------------------------------------------------
__global__ __launch_bounds__(512, 4) void fused_gemm_fill(
    const float* __restrict__ x, const ushort* __restrict__ Wcp,
    const float* __restrict__ b_l, const int* __restrict__ ei,
    int* __restrict__ cursor, ushort* __restrict__ colp,
    int* __restrict__ ovcnt, int2* __restrict__ over,
    ushort* __restrict__ yb, ushort* __restrict__ yrb) {
  __shared__ float xs[64 * 256];  // 64 KiB staging; epilogue aliases as bf16
  const int t = threadIdx.x;
  const int n0 = blockIdx.x * 64;
  const int l = t & 63;
  const int w = t >> 6;

  // --- 1. async stage x -> LDS (f32, source-chunk swizzled) ---
#pragma unroll
  for (int j = 0; j < 8; j++) {
    const int row = j * 8 + w;
    int gn = n0 + row;
    if (gn >= N_NODES) gn = N_NODES - 1;  // clamp; stores guarded
    const int sc = (l & ~7) | ((l & 7) ^ (row & 7));
    __builtin_amdgcn_global_load_lds(
        (const __attribute__((address_space(1))) unsigned int*)(
            x + (size_t)gn * 256 + sc * 4),
        (__attribute__((address_space(3))) unsigned int*)(xs + row * 256),
        16, 0, 0);
  }

  // --- 2. edge work (drains under staging wait; line-private counters) ---
  {
    const int stride = gridDim.x * 512;
    for (int e = blockIdx.x * 512 + t; e < N_EDGES; e += stride) {
      int src = ei[e];
      int dst = ei[N_EDGES + e];
      int pos = atomicAdd(&cursor[dst * CSTRIDE], 1);
      if (pos < CAP) {
        colp[dst * CAP + pos] = (ushort)src;
      } else {
        int o = atomicAdd(ovcnt, 1);
        if (o < MAX_OVER) over[o] = make_int2(dst, src);
      }
    }
  }

  const int wrow = w & 1;
  const int wcol = w >> 1;
  const int lq = l >> 4, l16 = l & 15;

  f32x4 acc[2][4];
#pragma unroll
  for (int a = 0; a < 2; a++)
#pragma unroll
    for (int b = 0; b < 4; b++) acc[a][b] = (f32x4){0.f, 0.f, 0.f, 0.f};

  // A-read bases: row rl, chunk pair (ks*8 + o0), o0 = (lq*2)^(rl&7).
  const float* ap0[2];
  const float* ap1[2];
#pragma unroll
  for (int nt = 0; nt < 2; nt++) {
    int rl = wrow * 32 + nt * 16 + l16;
    int o0 = (lq * 2) ^ (rl & 7);
    ap0[nt] = xs + rl * 256 + o0 * 4;
    ap1[nt] = xs + rl * 256 + (o0 ^ 1) * 4;
  }
  const ushort* bptr[4];
#pragma unroll
  for (int ct = 0; ct < 4; ct++) {
    int col = wcol * 64 + ct * 16 + l16;
    bptr[ct] = Wcp + ((size_t)col * 4 + lq) * 8;
  }

  // First B fragments before the barrier: overlap L2 latency with drain.
  s16x8 B[4], Bn[4];
#pragma unroll
  for (int ct = 0; ct < 4; ct++) B[ct] = *((const s16x8*)(bptr[ct]));

  __syncthreads();  // vmcnt(0)+lgkmcnt(0)+barrier: staging+edges+B complete

  union { s16x8 v; ushort4 u[2]; } ua;
#pragma unroll
  for (int ks = 0; ks < 8; ks++) {
    s16x8 A[2];
#pragma unroll
    for (int nt = 0; nt < 2; nt++) {
      float4 a0 = *((const float4*)(ap0[nt] + ks * 32));
      float4 a1 = *((const float4*)(ap1[nt] + ks * 32));
      __hip_bfloat162 h0 = __float22bfloat162_rn(make_float2(a0.x, a0.y));
      __hip_bfloat162 h1 = __float22bfloat162_rn(make_float2(a0.z, a0.w));
      __hip_bfloat162 h2 = __float22bfloat162_rn(make_float2(a1.x, a1.y));
      __hip_bfloat162 h3 = __float22bfloat162_rn(make_float2(a1.z, a1.w));
      ua.u[0].x = ((ushort2*)&h0)->x; ua.u[0].y = ((ushort2*)&h0)->y;
      ua.u[0].z = ((ushort2*)&h1)->x; ua.u[0].w = ((ushort2*)&h1)->y;
      ua.u[1].x = ((ushort2*)&h2)->x; ua.u[1].y = ((ushort2*)&h2)->y;
      ua.u[1].z = ((ushort2*)&h3)->x; ua.u[1].w = ((ushort2*)&h3)->y;
      A[nt] = ua.v;
    }
    if (ks < 7) {
#pragma unroll
      for (int ct = 0; ct < 4; ct++)
        Bn[ct] = *((const s16x8*)(bptr[ct] + (size_t)(ks + 1) * 256 * 32));
    }
#pragma unroll
    for (int nt = 0; nt < 2; nt++)
#pragma unroll
      for (int ct = 0; ct < 4; ct++)
        acc[nt][ct] = __builtin_amdgcn_mfma_f32_16x16x32_bf16(
            A[nt], B[ct], acc[nt][ct], 0, 0, 0);
#pragma unroll
    for (int ct = 0; ct < 4; ct++) B[ct] = Bn[ct];
  }

  // --- Epilogue: acc -> LDS bf16 (padded) -> vectorized b128 stores ---
  // C/D layout: col = lane&15, row = (lane>>4)*4 + reg  [m89/m91-verified]
  __syncthreads();  // all A-reads of xs complete before aliasing
  ushort* eb = (ushort*)xs;  // [64][264] bf16 = 33792 B < 64 KiB
#pragma unroll
  for (int nt = 0; nt < 2; nt++) {
#pragma unroll
    for (int ct = 0; ct < 4; ct++) {
      int col = wcol * 64 + ct * 16 + l16;  // 0..255
      float bias = (col >= 128) ? b_l[col - 128] : 0.f;
#pragma unroll
      for (int r = 0; r < 4; r++) {
        int rl = wrow * 32 + nt * 16 + lq * 4 + r;
        eb[rl * 264 + col] = f2bf(acc[nt][ct][r] + bias);
      }
    }
  }
  __syncthreads();
#pragma unroll
  for (int p = 0; p < 4; p++) {
    int id2 = p * 512 + t;      // 0..2047
    int rl = id2 >> 5;          // 0..63
    int c8 = (id2 & 31) * 8;    // 0..248
    int gn = n0 + rl;
    if (gn < N_NODES) {
      s16x8 v = *((const s16x8*)(eb + rl * 264 + c8));
      if (c8 < 128)
        *((s16x8*)(yb + (size_t)gn * D_GNN + c8)) = v;
      else
        *((s16x8*)(yrb + (size_t)gn * D_GNN + (c8 - 128))) = v;
    }
  }
}

// ---------------------------------------------------------------------------
// Gather (padded adjacency, ushort cols) + epilogue + pred head. One wave per
// node; lane owns dims {2*lane, 2*lane+1}. True degree = cursor[node*CSTRIDE];
// first min(deg,CAP) neighbors in colp[node*CAP..] (one 64B line), rest in
// the exact overflow list (wave-uniform scan, expected ~0 entries).
// ---------------------------------------------------------------------------
__global__ __launch_bounds__(256) void gather_pred(
    const int* __restrict__ cursor, const ushort* __restrict__ colp,
    const int* __restrict__ ovcnt, const int2* __restrict__ over,
    const ushort* __restrict__ yb, const ushort* __restrict__ yrb,
    const float* __restrict__ Wfc, const float* __restrict__ bfc,
    float* __restrict__ h, float* __restrict__ pred) {
  const int node = (blockIdx.x * 256 + threadIdx.x) >> 6;
  const int lane = threadIdx.x & 63;
  if (node >= N_NODES) return;
  const int degt = cursor[node * CSTRIDE];
  const int m = min(degt, CAP);
  float ax = 0.f, ay = 0.f;
  const unsigned int* y32 = (const unsigned int*)yb;

  int c = (lane < m) ? (int)colp[node * CAP + lane] : 0;
  int j = 0;
  for (; j + 4 <= m; j += 4) {
    int s0 = __shfl(c, j), s1 = __shfl(c, j + 1);
    int s2 = __shfl(c, j + 2), s3 = __shfl(c, j + 3);
    unsigned int v0 = y32[(size_t)s0 * 64 + lane];
    unsigned int v1 = y32[(size_t)s1 * 64 + lane];
    unsigned int v2 = y32[(size_t)s2 * 64 + lane];
    unsigned int v3 = y32[(size_t)s3 * 64 + lane];
    ax += __uint_as_float(v0 << 16) + __uint_as_float(v1 << 16) +
          __uint_as_float(v2 << 16) + __uint_as_float(v3 << 16);
    ay += __uint_as_float(v0 & 0xFFFF0000u) + __uint_as_float(v1 & 0xFFFF0000u) +
          __uint_as_float(v2 & 0xFFFF0000u) + __uint_as_float(v3 & 0xFFFF0000u);
  }
  for (; j < m; j++) {
    int s0 = __shfl(c, j);
    unsigned int v0 = y32[(size_t)s0 * 64 + lane];
    ax += __uint_as_float(v0 << 16);
    ay += __uint_as_float(v0 & 0xFFFF0000u);
  }
  if (degt > CAP) {  // exact overflow handling (rare; wave-uniform)
    int nov = min(ovcnt[0], MAX_OVER);
    for (int k = 0; k < nov; k++) {
      int2 ov = over[k];
      if (ov.x == node) {
        unsigned int v0 = y32[(size_t)ov.y * 64 + lane];
        ax += __uint_as_float(v0 << 16);
        ay += __uint_as_float(v0 & 0xFFFF0000u);
      }
    }
  }

  const float ic = degt > 0 ? 1.f / (float)degt : 0.f;
  unsigned int yrv = ((const unsigned int*)yrb)[(size_t)node * 64 + lane];
  float h0 = ax * ic + __uint_as_float(yrv << 16);
  float h1 = ay * ic + __uint_as_float(yrv & 0xFFFF0000u);
  float2 hv; hv.x = h0; hv.y = h1;
  ((float2*)h)[(size_t)node * 64 + lane] = hv;
  float s = h0 * Wfc[2 * lane] + h1 * Wfc[2 * lane + 1];
#pragma unroll
  for (int off = 32; off > 0; off >>= 1) s += __shfl_down(s, off);
  if (lane == 0) pred[node] = 1.f / (1.f + expf(-(s + bfc[0])));
}

extern "C" void kernel_launch(void* const* d_in, const int* in_sizes, int n_in,
                              void* d_out, int out_size, void* d_ws,
                              size_t ws_size, hipStream_t stream) {
  const float* x   = (const float*)d_in[0];
  const int*   ei  = (const int*)d_in[1];
  const float* Wl  = (const float*)d_in[2];
  const float* bl  = (const float*)d_in[3];
  const float* Wr  = (const float*)d_in[4];
  const float* Wfc = (const float*)d_in[5];
  const float* bfc = (const float*)d_in[6];

  float* out  = (float*)d_out;
  float* h    = out;                        // [N,128] final h (f32)
  float* pred = out + (size_t)N_NODES * D_GNN;

  ushort* Wcp   = (ushort*)d_ws;                              // 128 KB
  ushort* yb    = Wcp + 8192 * 8;                             // [N,128] bf16
  ushort* yrb   = yb + (size_t)N_NODES * D_GNN;               // [N,128] bf16
  int*   cursor = (int*)(yrb + (size_t)N_NODES * D_GNN);      // [N*CSTRIDE]
  int*   ovcnt  = cursor + N_NODES * CSTRIDE;                 // [1]
  int2*  over   = (int2*)(ovcnt + 1);                         // [MAX_OVER]
  ushort* colp  = (ushort*)(over + MAX_OVER);                 // [N*CAP] ushort

  // --- prologue: zero padded cursor/ovcnt + pack W ---
  pack0<<<(N_NODES * CSTRIDE + 255) / 256, 256, 0, stream>>>(
      Wl, Wr, Wcp, cursor, ovcnt);

  // --- fused: adjacency build (overlapped, line-private counters) + GEMM ---
  fused_gemm_fill<<<(N_NODES + 63) / 64, 512, 0, stream>>>(
      x, Wcp, bl, ei, cursor, colp, ovcnt, over, yb, yrb);

  // --- mean gather + h epilogue + pred head ---
  gather_pred<<<(N_NODES * 64 + 255) / 256, 256, 0, stream>>>(
      cursor, colp, ovcnt, over, yb, yrb, Wfc, bfc, h, pred);
}